// Round 2
// baseline (92.148 us; speedup 1.0000x reference)
//
#include <hip/hip_runtime.h>

// spikes = (floor(c_t) - floor(c_{t-1})) / DT,  c_t = v0 + cumsum(relu(x)*DT)
// Shapes: inputs [16, 2048, 1024] f32, initial_state [16, 1024] f32.
//
// The grading reference ("ref=np") is a float64 numpy recomputation of the
// formula. An fp32 scan (even bit-exactly matching jnp's fp32 order) drifts
// ~3e-6 over T=2048 and flips ~100s of floors vs the f64 reference
// (absmax 1000 > threshold 20, observed R0/R1). So: do the scan in double,
// replicating numpy f64 op order exactly:
//   rate_t = fmax((double)x, 0.0) * 0.001      (rounded per element)
//   S_t    = S_{t-1} + rate_t                   (sequential f64 cumsum)
//   c_t    = v0 + S_t ;  fl_t = floor(c_t)
//   out_t  = (fl_t - fl_{t-1}) * 1000.0         (vs np's /0.001: diff ~1e-13)
// One thread per (b,d) chain; 16384 chains = 256 waves = 1 wave/CU.

#pragma clang fp contract(off)   // np rounds rate before accumulating: no FMA

constexpr int B = 16;
constexpr int T = 2048;
constexpr int D = 1024;
constexpr int U = 32;            // prefetch chunk depth (t-steps)

__global__ __launch_bounds__(64, 1)
void spike_scan_kernel(const float* __restrict__ in,
                       const float* __restrict__ state,
                       float* __restrict__ out) {
  const int id = blockIdx.x * 64 + threadIdx.x;   // lane = consecutive d
  const int b = id >> 10;                         // D = 1024
  const int d = id & (D - 1);
  const size_t base = (size_t)b * T * D + d;
  const float* __restrict__ ip = in + base;
  float* __restrict__ op = out + base;

  const double v0 = (double)state[id];
  double s = 0.0;                 // f64 running cumsum of rates
  double prev = floor(v0);        // floor(c_{t-1}), seeded with floor(v0)

  float bufA[U], bufB[U];         // keep staged data in f32 (half the VGPRs)

  // Preload chunk 0.
#pragma unroll
  for (int u = 0; u < U; ++u) bufA[u] = ip[(size_t)u * D];

  for (int t = 0; t < T; t += 2 * U) {
    // Prefetch chunk t+U while computing chunk t.
#pragma unroll
    for (int u = 0; u < U; ++u) bufB[u] = ip[(size_t)(t + U + u) * D];

#pragma unroll
    for (int u = 0; u < U; ++u) {
      const double rate = fmax((double)bufA[u], 0.0) * 0.001;
      s += rate;
      const double fl = floor(v0 + s);
      op[(size_t)(t + u) * D] = (float)((fl - prev) * 1000.0);
      prev = fl;
    }

    // Prefetch chunk t+2U while computing chunk t+U.
    if (t + 2 * U < T) {
#pragma unroll
      for (int u = 0; u < U; ++u) bufA[u] = ip[(size_t)(t + 2 * U + u) * D];
    }

#pragma unroll
    for (int u = 0; u < U; ++u) {
      const double rate = fmax((double)bufB[u], 0.0) * 0.001;
      s += rate;
      const double fl = floor(v0 + s);
      op[(size_t)(t + U + u) * D] = (float)((fl - prev) * 1000.0);
      prev = fl;
    }
  }
}

extern "C" void kernel_launch(void* const* d_in, const int* in_sizes, int n_in,
                              void* d_out, int out_size, void* d_ws, size_t ws_size,
                              hipStream_t stream) {
  const float* in = (const float*)d_in[0];     // [B, T, D] f32
  const float* st = (const float*)d_in[1];     // [B, D]    f32
  float* out = (float*)d_out;                  // [B, T, D] f32

  // 16384 chains -> 256 blocks x 64 threads: 1 wave per CU, all 256 CUs busy.
  dim3 grid(B * D / 64);
  dim3 block(64);
  spike_scan_kernel<<<grid, block, 0, stream>>>(in, st, out);
}

// Round 3
// 57.450 us; speedup vs baseline: 1.6040x; 1.6040x over previous
//
#include <hip/hip_runtime.h>

// spikes = (floor(v0 + cumsum(relu(x)*DT)) - floor(prev)) / DT, f64 scan
// (f32 scan flips floors vs the f64 np reference — R0/R1 failures).
//
// R2 passed at 111us but latency-bound: 1 wave/CU (2.7% occupancy), writes
// at 1.2 TB/s. Fix: f64 is reassociable within ~1e-16, so split T into 16
// segments; 16 waves/block do a two-phase scan:
//   Phase 1: wave w computes in-order f64 sum of rates over its segment.
//   Phase 2: prefix = in-order sum of segsum[0..w-1] from LDS; re-read input
//            (L2/LLC-resident) and emit.  16 waves/CU -> 16x memory ILP.

#pragma clang fp contract(off)   // np rounds rate before accumulating: no FMA

constexpr int B = 16;
constexpr int T = 2048;
constexpr int D = 1024;
constexpr int NSEG = 16;          // waves per block == T segments
constexpr int TSEG = T / NSEG;    // 128 steps per segment
constexpr int U = 16;             // prefetch chunk depth

__global__ __launch_bounds__(1024, 4)
void spike_scan_kernel(const float* __restrict__ in,
                       const float* __restrict__ state,
                       float* __restrict__ out) {
  const int lane = threadIdx.x & 63;
  const int wave = threadIdx.x >> 6;              // segment index 0..15
  const int id = blockIdx.x * 64 + lane;          // chain id; lane = consec d
  const int b = id >> 10;                         // D = 1024
  const int d = id & (D - 1);
  const size_t base = (size_t)b * T * D + d + (size_t)wave * TSEG * D;
  const float* __restrict__ ip = in + base;
  float* __restrict__ op = out + base;

  __shared__ double segsum[NSEG][64];             // 8 KB

  // ---- Phase 1: in-order f64 sum of rates over this wave's segment ----
  double ssum = 0.0;
  float bufA[U], bufB[U];
#pragma unroll
  for (int u = 0; u < U; ++u) bufA[u] = ip[(size_t)u * D];
  for (int t = 0; t < TSEG; t += 2 * U) {
#pragma unroll
    for (int u = 0; u < U; ++u) bufB[u] = ip[(size_t)(t + U + u) * D];
#pragma unroll
    for (int u = 0; u < U; ++u) ssum += fmax((double)bufA[u], 0.0) * 0.001;
    if (t + 2 * U < TSEG) {
#pragma unroll
      for (int u = 0; u < U; ++u) bufA[u] = ip[(size_t)(t + 2 * U + u) * D];
    }
#pragma unroll
    for (int u = 0; u < U; ++u) ssum += fmax((double)bufB[u], 0.0) * 0.001;
  }
  segsum[wave][lane] = ssum;
  __syncthreads();

  // ---- Phase 2: segment prefix (in order), then emit this segment ----
  const double v0 = (double)state[id];
  double s = 0.0;                                 // rate-sum before my segment
  for (int w = 0; w < wave; ++w) s += segsum[w][lane];
  double prev = floor(v0 + s);                    // wave 0: floor(v0)  ✓

#pragma unroll
  for (int u = 0; u < U; ++u) bufA[u] = ip[(size_t)u * D];
  for (int t = 0; t < TSEG; t += 2 * U) {
#pragma unroll
    for (int u = 0; u < U; ++u) bufB[u] = ip[(size_t)(t + U + u) * D];
#pragma unroll
    for (int u = 0; u < U; ++u) {
      s += fmax((double)bufA[u], 0.0) * 0.001;
      const double fl = floor(v0 + s);
      op[(size_t)(t + u) * D] = (float)((fl - prev) * 1000.0);
      prev = fl;
    }
    if (t + 2 * U < TSEG) {
#pragma unroll
      for (int u = 0; u < U; ++u) bufA[u] = ip[(size_t)(t + 2 * U + u) * D];
    }
#pragma unroll
    for (int u = 0; u < U; ++u) {
      s += fmax((double)bufB[u], 0.0) * 0.001;
      const double fl = floor(v0 + s);
      op[(size_t)(t + U + u) * D] = (float)((fl - prev) * 1000.0);
      prev = fl;
    }
  }
}

extern "C" void kernel_launch(void* const* d_in, const int* in_sizes, int n_in,
                              void* d_out, int out_size, void* d_ws, size_t ws_size,
                              hipStream_t stream) {
  const float* in = (const float*)d_in[0];     // [B, T, D] f32
  const float* st = (const float*)d_in[1];     // [B, D]    f32
  float* out = (float*)d_out;                  // [B, T, D] f32

  // 16384 chains / 64 lanes = 256 blocks; 16 waves each (one per T-segment).
  dim3 grid(B * D / 64);
  dim3 block(NSEG * 64);
  spike_scan_kernel<<<grid, block, 0, stream>>>(in, st, out);
}